// Round 9
// baseline (305.011 us; speedup 1.0000x reference)
//
#include <hip/hip_runtime.h>
#include <math.h>

#define WAVE 64
#define NEG_SLOPE 0.2f
#define LSTR 68  // padded LDS row stride (dwords)

// ---------------------------------------------------------------------------
// CSR build via two-level counting sort (bucket = 128 consecutive dst nodes).
// ---------------------------------------------------------------------------

__global__ __launch_bounds__(256) void bucket_count_kernel(
    const int* __restrict__ dst, int* __restrict__ gcnt, int e, int nb) {
    extern __shared__ int cnt[];
    for (int b = threadIdx.x; b < nb; b += 256) cnt[b] = 0;
    __syncthreads();
    int base = blockIdx.x * 4096;
#pragma unroll
    for (int k = 0; k < 16; ++k) {
        int i = base + k * 256 + threadIdx.x;
        if (i < e) atomicAdd(&cnt[dst[i] >> 7], 1);
    }
    __syncthreads();
    for (int b = threadIdx.x; b < nb; b += 256) {
        int c = cnt[b];
        if (c) atomicAdd(&gcnt[b], c);
    }
}

__global__ __launch_bounds__(512) void bucket_scan_kernel(
    const int* __restrict__ gcnt, int* __restrict__ boff, int* __restrict__ gfill,
    int* __restrict__ rowptr, int nb, int e, int n) {
    __shared__ int sh[512];
    int t = threadIdx.x;
    int v = (t < nb) ? gcnt[t] : 0;
    sh[t] = v;
    __syncthreads();
    for (int o = 1; o < 512; o <<= 1) {
        int u = (t >= o) ? sh[t - o] : 0;
        __syncthreads();
        sh[t] += u;
        __syncthreads();
    }
    if (t < nb) { int ex = sh[t] - v; boff[t] = ex; gfill[t] = ex; }
    if (t == 0) { boff[nb] = e; rowptr[n] = e + n; }
}

__global__ __launch_bounds__(256) void bucket_place_kernel(
    const int* __restrict__ src, const int* __restrict__ dst,
    int* __restrict__ gfill, int2* __restrict__ binned, int e, int nb) {
    extern __shared__ int lds[];
    int* cnt = lds;        // [nb]
    int* bas = lds + nb;   // [nb]
    for (int b = threadIdx.x; b < nb; b += 256) cnt[b] = 0;
    __syncthreads();
    int base = blockIdx.x * 4096;
#pragma unroll
    for (int k = 0; k < 16; ++k) {
        int i = base + k * 256 + threadIdx.x;
        if (i < e) atomicAdd(&cnt[dst[i] >> 7], 1);
    }
    __syncthreads();
    for (int b = threadIdx.x; b < nb; b += 256) {
        int c = cnt[b];
        bas[b] = c ? atomicAdd(&gfill[b], c) : 0;
        cnt[b] = 0;
    }
    __syncthreads();
#pragma unroll
    for (int k = 0; k < 16; ++k) {
        int i = base + k * 256 + threadIdx.x;
        if (i < e) {
            int d = dst[i];
            int bk = d >> 7;
            int r = atomicAdd(&cnt[bk], 1);
            binned[bas[bk] + r] = make_int2(src[i], d);
        }
    }
}

__global__ __launch_bounds__(256) void bucket_build_kernel(
    const int2* __restrict__ binned, const int* __restrict__ boff,
    int* __restrict__ csr_src, int* __restrict__ rowptr, int n) {
    __shared__ int cnt[128], off[128], pcnt[128];
    int b = blockIdx.x;
    int t = threadIdx.x;
    int nodeBase = b << 7;
    int nc = min(128, n - nodeBase);
    int e0 = boff[b], e1 = boff[b + 1];
    int ne = e1 - e0;
    if (t < 128) { cnt[t] = 1; pcnt[t] = 1; }  // self-loop reserves slot 0
    __syncthreads();
    for (int i = t; i < ne; i += 256)
        atomicAdd(&cnt[binned[e0 + i].y - nodeBase], 1);
    __syncthreads();
    if (t < 128) off[t] = cnt[t];
    __syncthreads();
    for (int o = 1; o < 128; o <<= 1) {
        int u = (t >= o && t < 128) ? off[t - o] : 0;
        __syncthreads();
        if (t < 128) off[t] += u;
        __syncthreads();
    }
    if (t < 128) off[t] -= cnt[t];  // exclusive
    __syncthreads();
    int csrBase = e0 + nodeBase;
    if (t < nc) {
        rowptr[nodeBase + t] = csrBase + off[t];
        csr_src[csrBase + off[t]] = nodeBase + t;  // self loop
    }
    for (int i = t; i < ne; i += 256) {
        int2 p = binned[e0 + i];
        int loc = p.y - nodeBase;
        int r = atomicAdd(&pcnt[loc], 1);
        csr_src[csrBase + off[loc] + r] = p.x;
    }
}

// ---------------------------------------------------------------------------
// Device helper: full-wave GAT aggregation for ONE dst node.
// Returns the normalized+bias(+relu) float4 for (eg==0) lanes; other lanes
// return garbage. Layout: 4 edge-slots (eg) x 16 channel-groups (cg).
// Tail loads are masked (idx < nch) so w=0 slots issue no L1 transactions.
// ---------------------------------------------------------------------------
__device__ __forceinline__ float4 gat_node(
    const float* __restrict__ H, const float* __restrict__ S,
    const int* __restrict__ rowptr, const int* __restrict__ csr_src,
    const float* __restrict__ D, const float4 bv, int wid, int lane,
    int do_relu) {
    int eg = lane >> 4;
    int cg = lane & 15;
    int start = rowptr[wid];
    int end   = rowptr[wid + 1];
    float d_i = D[wid];

    float z = 0.f;
    float4 acc = make_float4(0.f, 0.f, 0.f, 0.f);

    for (int cb = start; cb < end; cb += WAVE) {
        // Phase 1: lane = edge; coalesced csr load, S gather, exp
        int j = cb + lane;
        bool v = j < end;
        int sc = v ? csr_src[j] : 0;
        float sv = S[sc];
        float e = sv + d_i;
        e = (e > 0.f) ? e : NEG_SLOPE * e;
        float w = v ? __expf(e) : 0.f;

        // Phase 2: 4 edges/round; masked loads kill tail transactions
        int nch = min(WAVE, end - cb);
        int rounds = (nch + 3) >> 2;
#pragma unroll 4
        for (int r = 0; r < rounds; ++r) {
            int idx = 4 * r + eg;
            float wr = __shfl(w, idx);
            int   sr = __shfl(sc, idx);
            float4 hv = make_float4(0.f, 0.f, 0.f, 0.f);
            if (idx < nch) hv = *(const float4*)(H + (size_t)sr * 64 + 4 * cg);
            z += wr;
            acc.x = fmaf(wr, hv.x, acc.x);
            acc.y = fmaf(wr, hv.y, acc.y);
            acc.z = fmaf(wr, hv.z, acc.z);
            acc.w = fmaf(wr, hv.w, acc.w);
        }
    }

    for (int o = 16; o < 64; o <<= 1) {
        acc.x += __shfl_xor(acc.x, o);
        acc.y += __shfl_xor(acc.y, o);
        acc.z += __shfl_xor(acc.z, o);
        acc.w += __shfl_xor(acc.w, o);
        z     += __shfl_xor(z, o);
    }

    float inv = 1.f / (z + 1e-16f);
    float4 o4;
    o4.x = acc.x * inv + bv.x;
    o4.y = acc.y * inv + bv.y;
    o4.z = acc.z * inv + bv.z;
    o4.w = acc.w * inv + bv.w;
    if (do_relu) {
        o4.x = fmaxf(o4.x, 0.f); o4.y = fmaxf(o4.y, 0.f);
        o4.z = fmaxf(o4.z, 0.f); o4.w = fmaxf(o4.w, 0.f);
    }
    return o4;
}

// ---------------------------------------------------------------------------
// Layer-0 feature transform: H = X @ W (K=128); S,D logits.
// Register-tiled: 256 threads = 16x16, 4x4 micro-tile per thread.
// ---------------------------------------------------------------------------

__global__ __launch_bounds__(256) void gemm_feat_kernel(
    const float* __restrict__ X, const float* __restrict__ W,
    const float* __restrict__ a_s, const float* __restrict__ a_d,
    float* __restrict__ H, float* __restrict__ S, float* __restrict__ D, int n) {
    constexpr int K = 128;
    __shared__ float Xs[64 * LSTR];
    __shared__ float Ws[64 * LSTR];
    int t = threadIdx.x;
    int tx = t & 15;
    int ty = t >> 4;
    int base = blockIdx.x * 64;
    float acc[4][4] = {};

    int q = t & 3;
    int srow = t >> 2;

    for (int k0 = 0; k0 < K; k0 += 64) {
        int grow = base + srow;
#pragma unroll
        for (int j = 0; j < 4; ++j) {
            int c = 16 * j + 4 * q;
            float4 v = make_float4(0.f, 0.f, 0.f, 0.f);
            if (grow < n) v = *(const float4*)(X + (size_t)grow * K + k0 + c);
            *(float4*)(Xs + srow * LSTR + c) = v;
            float4 w = *(const float4*)(W + (size_t)(k0 + srow) * 64 + c);
            *(float4*)(Ws + srow * LSTR + c) = w;
        }
        __syncthreads();
#pragma unroll 8
        for (int kk = 0; kk < 64; ++kk) {
            float4 wv = *(const float4*)(Ws + kk * LSTR + 4 * tx);
#pragma unroll
            for (int i = 0; i < 4; ++i) {
                float xv = Xs[(4 * ty + i) * LSTR + kk];
                acc[i][0] = fmaf(xv, wv.x, acc[i][0]);
                acc[i][1] = fmaf(xv, wv.y, acc[i][1]);
                acc[i][2] = fmaf(xv, wv.z, acc[i][2]);
                acc[i][3] = fmaf(xv, wv.w, acc[i][3]);
            }
        }
        __syncthreads();
    }

    const float4 av_s = *(const float4*)(a_s + 4 * tx);
    const float4 av_d = *(const float4*)(a_d + 4 * tx);
#pragma unroll
    for (int i = 0; i < 4; ++i) {
        int row = base + 4 * ty + i;
        bool ok = row < n;
        if (ok) {
            float4 hv = make_float4(acc[i][0], acc[i][1], acc[i][2], acc[i][3]);
            *(float4*)(H + (size_t)row * 64 + 4 * tx) = hv;
        }
        float ps = acc[i][0] * av_s.x + acc[i][1] * av_s.y +
                   acc[i][2] * av_s.z + acc[i][3] * av_s.w;
        float pd = acc[i][0] * av_d.x + acc[i][1] * av_d.y +
                   acc[i][2] * av_d.z + acc[i][3] * av_d.w;
        for (int o = 1; o < 16; o <<= 1) {
            ps += __shfl_xor(ps, o);
            pd += __shfl_xor(pd, o);
        }
        if (tx == 0 && ok) { S[row] = ps; D[row] = pd; }
    }
}

// ---------------------------------------------------------------------------
// Fused: agg(layer l) for 64 nodes -> Xs LDS tile -> gemm(layer l+1, K=64).
// The block's agg outputs are exactly the gemm tile's X rows: no global
// round-trip for the inter-layer activations, no X staging in the gemm.
// ---------------------------------------------------------------------------

__global__ __launch_bounds__(256) void agg_gemm_kernel(
    const float* __restrict__ H, const float* __restrict__ S,
    const float* __restrict__ D, const int* __restrict__ rowptr,
    const int* __restrict__ csr_src, const float* __restrict__ bias,
    const float* __restrict__ W, const float* __restrict__ a_s,
    const float* __restrict__ a_d, float* __restrict__ Hout,
    float* __restrict__ Sout, float* __restrict__ Dout, int n) {
    __shared__ float Xs[64 * LSTR];
    __shared__ float Ws[64 * LSTR];
    int t = threadIdx.x;
    int lane = t & 63;
    int wv = t >> 6;       // wave 0..3
    int base = blockIdx.x * 64;

    // stage W (K=64) into Ws: independent of phase A, issued first
    {
        int q = t & 3;
        int srow = t >> 2;
#pragma unroll
        for (int j = 0; j < 4; ++j) {
            int c = 16 * j + 4 * q;
            float4 w = *(const float4*)(W + (size_t)srow * 64 + c);
            *(float4*)(Ws + srow * LSTR + c) = w;
        }
    }

    // Phase A: aggregation, one wave per node, 16 nodes per wave
    int eg = lane >> 4;
    int cg = lane & 15;
    const float4 bv = *(const float4*)(bias + 4 * cg);
    for (int local = wv; local < 64; local += 4) {
        int wid = base + local;
        if (wid < n) {
            float4 o4 = gat_node(H, S, rowptr, csr_src, D, bv, wid, lane, 1);
            if (eg == 0) *(float4*)(Xs + local * LSTR + 4 * cg) = o4;
        } else if (eg == 0) {
            *(float4*)(Xs + local * LSTR + 4 * cg) = make_float4(0.f, 0.f, 0.f, 0.f);
        }
    }
    __syncthreads();

    // Phase B: gemm on the LDS tile (K=64)
    int tx = t & 15;
    int ty = t >> 4;
    float acc[4][4] = {};
#pragma unroll 8
    for (int kk = 0; kk < 64; ++kk) {
        float4 wvv = *(const float4*)(Ws + kk * LSTR + 4 * tx);
#pragma unroll
        for (int i = 0; i < 4; ++i) {
            float xv = Xs[(4 * ty + i) * LSTR + kk];
            acc[i][0] = fmaf(xv, wvv.x, acc[i][0]);
            acc[i][1] = fmaf(xv, wvv.y, acc[i][1]);
            acc[i][2] = fmaf(xv, wvv.z, acc[i][2]);
            acc[i][3] = fmaf(xv, wvv.w, acc[i][3]);
        }
    }

    const float4 av_s = *(const float4*)(a_s + 4 * tx);
    const float4 av_d = *(const float4*)(a_d + 4 * tx);
#pragma unroll
    for (int i = 0; i < 4; ++i) {
        int row = base + 4 * ty + i;
        bool ok = row < n;
        if (ok) {
            float4 hv = make_float4(acc[i][0], acc[i][1], acc[i][2], acc[i][3]);
            *(float4*)(Hout + (size_t)row * 64 + 4 * tx) = hv;
        }
        float ps = acc[i][0] * av_s.x + acc[i][1] * av_s.y +
                   acc[i][2] * av_s.z + acc[i][3] * av_s.w;
        float pd = acc[i][0] * av_d.x + acc[i][1] * av_d.y +
                   acc[i][2] * av_d.z + acc[i][3] * av_d.w;
        for (int o = 1; o < 16; o <<= 1) {
            ps += __shfl_xor(ps, o);
            pd += __shfl_xor(pd, o);
        }
        if (tx == 0 && ok) { Sout[row] = ps; Dout[row] = pd; }
    }
}

// ---------------------------------------------------------------------------
// Final standalone aggregation (layer 2, no relu) -> d_out.
// ---------------------------------------------------------------------------

__global__ __launch_bounds__(256) void gat_aggregate_kernel(
    const float* __restrict__ H, const float* __restrict__ S,
    const float* __restrict__ D, const int* __restrict__ rowptr,
    const int* __restrict__ csr_src, const float* __restrict__ bias,
    float* __restrict__ OUT, int n) {
    int wid  = (blockIdx.x * blockDim.x + threadIdx.x) >> 6;
    int lane = threadIdx.x & 63;
    if (wid >= n) return;
    int eg = lane >> 4;
    int cg = lane & 15;
    const float4 bv = *(const float4*)(bias + 4 * cg);
    float4 o4 = gat_node(H, S, rowptr, csr_src, D, bv, wid, lane, 0);
    if (eg == 0) *(float4*)(OUT + (size_t)wid * 64 + 4 * cg) = o4;
}

// ---------------------------------------------------------------------------

static inline size_t align256(size_t x) { return (x + 255) & ~(size_t)255; }

extern "C" void kernel_launch(void* const* d_in, const int* in_sizes, int n_in,
                              void* d_out, int out_size, void* d_ws, size_t ws_size,
                              hipStream_t stream) {
    const float* x    = (const float*)d_in[0];
    const int*   esrc = (const int*)d_in[1];
    const int*   edst = (const int*)d_in[2];
    const int E = in_sizes[1];
    const int N = in_sizes[0] / 128;

    const float* W0 = (const float*)d_in[3];
    const float* as0 = (const float*)d_in[4];
    const float* ad0 = (const float*)d_in[5];
    const float* b0 = (const float*)d_in[6];
    const float* W1 = (const float*)d_in[7];
    const float* as1 = (const float*)d_in[8];
    const float* ad1 = (const float*)d_in[9];
    const float* b1 = (const float*)d_in[10];
    const float* W2 = (const float*)d_in[11];
    const float* as2 = (const float*)d_in[12];
    const float* ad2 = (const float*)d_in[13];
    const float* b2 = (const float*)d_in[14];

    const int NB = (N + 127) >> 7;  // buckets of 128 nodes (<=512 for scan)

    // workspace layout
    char* p = (char*)d_ws;
    int* gcnt    = (int*)p; p += align256((size_t)(NB + 1) * 4);
    int* boff    = (int*)p; p += align256((size_t)(NB + 1) * 4);
    int* gfill   = (int*)p; p += align256((size_t)(NB + 1) * 4);
    int* rowptr  = (int*)p; p += align256((size_t)(N + 1) * 4);
    int* csr_src = (int*)p; p += align256((size_t)(E + N) * 4);
    int2* binned = (int2*)p; p += align256((size_t)E * 8);
    float* hA = (float*)p; p += align256((size_t)N * 64 * 4);
    float* hB = (float*)p; p += align256((size_t)N * 64 * 4);
    float* sA = (float*)p; p += align256((size_t)N * 4);
    float* dA = (float*)p; p += align256((size_t)N * 4);
    float* sB = (float*)p; p += align256((size_t)N * 4);
    float* dB = (float*)p; p += align256((size_t)N * 4);
    float* out = (float*)d_out;

    // ---- CSR build (two-level counting sort) ----
    int nchunk = (E + 4095) / 4096;
    hipMemsetAsync(gcnt, 0, (size_t)(NB + 1) * 4, stream);
    bucket_count_kernel<<<nchunk, 256, NB * 4, stream>>>(edst, gcnt, E, NB);
    bucket_scan_kernel<<<1, 512, 0, stream>>>(gcnt, boff, gfill, rowptr, NB, E, N);
    bucket_place_kernel<<<nchunk, 256, 2 * NB * 4, stream>>>(esrc, edst, gfill, binned, E, NB);
    bucket_build_kernel<<<NB, 256, 0, stream>>>(binned, boff, csr_src, rowptr, N);

    int tile_grid = (N + 63) / 64;
    int agg_grid  = (N + 3) / 4;

    // L0 gemm: x @ W0 -> hA, sA, dA
    gemm_feat_kernel<<<tile_grid, 256, 0, stream>>>(x, W0, as0, ad0, hA, sA, dA, N);
    // agg L0 (relu, b0) fused with gemm L1 -> hB, sB, dB
    agg_gemm_kernel<<<tile_grid, 256, 0, stream>>>(hA, sA, dA, rowptr, csr_src, b0,
                                                   W1, as1, ad1, hB, sB, dB, N);
    // agg L1 (relu, b1) fused with gemm L2 -> hA, sA, dA (ping-pong)
    agg_gemm_kernel<<<tile_grid, 256, 0, stream>>>(hB, sB, dB, rowptr, csr_src, b1,
                                                   W2, as2, ad2, hA, sA, dA, N);
    // final agg L2 (no relu, b2) -> out
    gat_aggregate_kernel<<<agg_grid, 256, 0, stream>>>(hA, sA, dA, rowptr, csr_src, b2, out, N);
}

// Round 10
// 272.339 us; speedup vs baseline: 1.1200x; 1.1200x over previous
//
#include <hip/hip_runtime.h>
#include <hip/hip_fp16.h>
#include <math.h>

#define WAVE 64
#define NEG_SLOPE 0.2f
#define LSTR 68  // padded LDS row stride (dwords)

// ---------------------------------------------------------------------------
// CSR build via two-level counting sort (bucket = 128 consecutive dst nodes).
// ---------------------------------------------------------------------------

__global__ __launch_bounds__(256) void bucket_count_kernel(
    const int* __restrict__ dst, int* __restrict__ gcnt, int e, int nb) {
    extern __shared__ int cnt[];
    for (int b = threadIdx.x; b < nb; b += 256) cnt[b] = 0;
    __syncthreads();
    int base = blockIdx.x * 4096;
#pragma unroll
    for (int k = 0; k < 16; ++k) {
        int i = base + k * 256 + threadIdx.x;
        if (i < e) atomicAdd(&cnt[dst[i] >> 7], 1);
    }
    __syncthreads();
    for (int b = threadIdx.x; b < nb; b += 256) {
        int c = cnt[b];
        if (c) atomicAdd(&gcnt[b], c);
    }
}

__global__ __launch_bounds__(512) void bucket_scan_kernel(
    const int* __restrict__ gcnt, int* __restrict__ boff, int* __restrict__ gfill,
    int* __restrict__ rowptr, int nb, int e, int n) {
    __shared__ int sh[512];
    int t = threadIdx.x;
    int v = (t < nb) ? gcnt[t] : 0;
    sh[t] = v;
    __syncthreads();
    for (int o = 1; o < 512; o <<= 1) {
        int u = (t >= o) ? sh[t - o] : 0;
        __syncthreads();
        sh[t] += u;
        __syncthreads();
    }
    if (t < nb) { int ex = sh[t] - v; boff[t] = ex; gfill[t] = ex; }
    if (t == 0) { boff[nb] = e; rowptr[n] = e + n; }
}

__global__ __launch_bounds__(256) void bucket_place_kernel(
    const int* __restrict__ src, const int* __restrict__ dst,
    int* __restrict__ gfill, int2* __restrict__ binned, int e, int nb) {
    extern __shared__ int lds[];
    int* cnt = lds;        // [nb]
    int* bas = lds + nb;   // [nb]
    for (int b = threadIdx.x; b < nb; b += 256) cnt[b] = 0;
    __syncthreads();
    int base = blockIdx.x * 4096;
#pragma unroll
    for (int k = 0; k < 16; ++k) {
        int i = base + k * 256 + threadIdx.x;
        if (i < e) atomicAdd(&cnt[dst[i] >> 7], 1);
    }
    __syncthreads();
    for (int b = threadIdx.x; b < nb; b += 256) {
        int c = cnt[b];
        bas[b] = c ? atomicAdd(&gfill[b], c) : 0;
        cnt[b] = 0;
    }
    __syncthreads();
#pragma unroll
    for (int k = 0; k < 16; ++k) {
        int i = base + k * 256 + threadIdx.x;
        if (i < e) {
            int d = dst[i];
            int bk = d >> 7;
            int r = atomicAdd(&cnt[bk], 1);
            binned[bas[bk] + r] = make_int2(src[i], d);
        }
    }
}

__global__ __launch_bounds__(256) void bucket_build_kernel(
    const int2* __restrict__ binned, const int* __restrict__ boff,
    int* __restrict__ csr_src, int* __restrict__ rowptr, int n) {
    __shared__ int cnt[128], off[128], pcnt[128];
    int b = blockIdx.x;
    int t = threadIdx.x;
    int nodeBase = b << 7;
    int nc = min(128, n - nodeBase);
    int e0 = boff[b], e1 = boff[b + 1];
    int ne = e1 - e0;
    if (t < 128) { cnt[t] = 1; pcnt[t] = 1; }  // self-loop reserves slot 0
    __syncthreads();
    for (int i = t; i < ne; i += 256)
        atomicAdd(&cnt[binned[e0 + i].y - nodeBase], 1);
    __syncthreads();
    if (t < 128) off[t] = cnt[t];
    __syncthreads();
    for (int o = 1; o < 128; o <<= 1) {
        int u = (t >= o && t < 128) ? off[t - o] : 0;
        __syncthreads();
        if (t < 128) off[t] += u;
        __syncthreads();
    }
    if (t < 128) off[t] -= cnt[t];  // exclusive
    __syncthreads();
    int csrBase = e0 + nodeBase;
    if (t < nc) {
        rowptr[nodeBase + t] = csrBase + off[t];
        csr_src[csrBase + off[t]] = nodeBase + t;  // self loop
    }
    for (int i = t; i < ne; i += 256) {
        int2 p = binned[e0 + i];
        int loc = p.y - nodeBase;
        int r = atomicAdd(&pcnt[loc], 1);
        csr_src[csrBase + off[loc] + r] = p.x;
    }
}

// ---------------------------------------------------------------------------
// Feature transform: H(fp16) = X @ W ;  S = H . a_src ;  D = H . a_dst
// Register-tiled: 256 threads = 16x16, 4x4 micro-tile per thread.
// H stored as fp16 (128B rows): halves the agg gather's L1 transactions.
// ---------------------------------------------------------------------------

template <int K>
__global__ __launch_bounds__(256) void gemm_feat_kernel(
    const float* __restrict__ X, const float* __restrict__ W,
    const float* __restrict__ a_s, const float* __restrict__ a_d,
    __half* __restrict__ H, float* __restrict__ S, float* __restrict__ D, int n) {
    __shared__ float Xs[64 * LSTR];
    __shared__ float Ws[64 * LSTR];
    int t = threadIdx.x;
    int tx = t & 15;
    int ty = t >> 4;
    int base = blockIdx.x * 64;
    float acc[4][4] = {};

    int q = t & 3;
    int srow = t >> 2;

    for (int k0 = 0; k0 < K; k0 += 64) {
        int grow = base + srow;
#pragma unroll
        for (int j = 0; j < 4; ++j) {
            int c = 16 * j + 4 * q;
            float4 v = make_float4(0.f, 0.f, 0.f, 0.f);
            if (grow < n) v = *(const float4*)(X + (size_t)grow * K + k0 + c);
            *(float4*)(Xs + srow * LSTR + c) = v;
            float4 w = *(const float4*)(W + (size_t)(k0 + srow) * 64 + c);
            *(float4*)(Ws + srow * LSTR + c) = w;
        }
        __syncthreads();
#pragma unroll 8
        for (int kk = 0; kk < 64; ++kk) {
            float4 wv = *(const float4*)(Ws + kk * LSTR + 4 * tx);
#pragma unroll
            for (int i = 0; i < 4; ++i) {
                float xv = Xs[(4 * ty + i) * LSTR + kk];
                acc[i][0] = fmaf(xv, wv.x, acc[i][0]);
                acc[i][1] = fmaf(xv, wv.y, acc[i][1]);
                acc[i][2] = fmaf(xv, wv.z, acc[i][2]);
                acc[i][3] = fmaf(xv, wv.w, acc[i][3]);
            }
        }
        __syncthreads();
    }

    const float4 av_s = *(const float4*)(a_s + 4 * tx);
    const float4 av_d = *(const float4*)(a_d + 4 * tx);
#pragma unroll
    for (int i = 0; i < 4; ++i) {
        int row = base + 4 * ty + i;
        bool ok = row < n;
        if (ok) {
            __half2 h01 = __floats2half2_rn(acc[i][0], acc[i][1]);
            __half2 h23 = __floats2half2_rn(acc[i][2], acc[i][3]);
            uint2 u;
            u.x = *(unsigned int*)&h01;
            u.y = *(unsigned int*)&h23;
            *(uint2*)(H + (size_t)row * 64 + 4 * tx) = u;  // 8B aligned
        }
        float ps = acc[i][0] * av_s.x + acc[i][1] * av_s.y +
                   acc[i][2] * av_s.z + acc[i][3] * av_s.w;
        float pd = acc[i][0] * av_d.x + acc[i][1] * av_d.y +
                   acc[i][2] * av_d.z + acc[i][3] * av_d.w;
        for (int o = 1; o < 16; o <<= 1) {
            ps += __shfl_xor(ps, o);
            pd += __shfl_xor(pd, o);
        }
        if (tx == 0 && ok) { S[row] = ps; D[row] = pd; }
    }
}

// ---------------------------------------------------------------------------
// GAT aggregation, one wave per dst node. No max-shift (logits O(+-10),
// fp32 exp cannot overflow). H gathered as fp16 (8B/lane), accumulate fp32.
// Phase 1 (lane=edge): coalesced csr load + S gather + exp.
// Phase 2 (4 edge-slots x 16 channel-groups): shfl-broadcast (w,src);
// masked 8B loads, unroll 4 -> 16 independent lines in flight per wave.
// ---------------------------------------------------------------------------

__global__ __launch_bounds__(256) void gat_aggregate_kernel(
    const __half* __restrict__ H, const float* __restrict__ S,
    const float* __restrict__ D, const int* __restrict__ rowptr,
    const int* __restrict__ csr_src, const float* __restrict__ bias,
    float* __restrict__ OUT, int n, int do_relu) {
    int wid  = (blockIdx.x * blockDim.x + threadIdx.x) >> 6;
    int lane = threadIdx.x & 63;
    if (wid >= n) return;
    int eg = lane >> 4;   // edge slot 0..3
    int cg = lane & 15;   // channel group: channels 4cg..4cg+3
    int start = rowptr[wid];
    int end   = rowptr[wid + 1];
    float d_i = D[wid];

    float z = 0.f;
    float4 acc = make_float4(0.f, 0.f, 0.f, 0.f);

    for (int cb = start; cb < end; cb += WAVE) {
        // Phase 1: lane = edge
        int j = cb + lane;
        bool v = j < end;
        int sc = v ? csr_src[j] : 0;
        float sv = S[sc];
        float e = sv + d_i;
        e = (e > 0.f) ? e : NEG_SLOPE * e;
        float w = v ? __expf(e) : 0.f;

        // Phase 2
        int nch = min(WAVE, end - cb);
        int rounds = (nch + 3) >> 2;
#pragma unroll 4
        for (int r = 0; r < rounds; ++r) {
            int idx = 4 * r + eg;
            float wr = __shfl(w, idx);
            int   sr = __shfl(sc, idx);
            float2 f0 = make_float2(0.f, 0.f), f1 = f0;
            if (idx < nch) {
                uint2 u = *(const uint2*)(H + (size_t)sr * 64 + 4 * cg);
                f0 = __half22float2(*(__half2*)&u.x);
                f1 = __half22float2(*(__half2*)&u.y);
            }
            z += wr;
            acc.x = fmaf(wr, f0.x, acc.x);
            acc.y = fmaf(wr, f0.y, acc.y);
            acc.z = fmaf(wr, f1.x, acc.z);
            acc.w = fmaf(wr, f1.y, acc.w);
        }
    }

    for (int o = 16; o < 64; o <<= 1) {
        acc.x += __shfl_xor(acc.x, o);
        acc.y += __shfl_xor(acc.y, o);
        acc.z += __shfl_xor(acc.z, o);
        acc.w += __shfl_xor(acc.w, o);
        z     += __shfl_xor(z, o);
    }

    if (eg == 0) {
        float inv = 1.f / (z + 1e-16f);
        const float4 bv = *(const float4*)(bias + 4 * cg);
        float4 o4;
        o4.x = acc.x * inv + bv.x;
        o4.y = acc.y * inv + bv.y;
        o4.z = acc.z * inv + bv.z;
        o4.w = acc.w * inv + bv.w;
        if (do_relu) {
            o4.x = fmaxf(o4.x, 0.f); o4.y = fmaxf(o4.y, 0.f);
            o4.z = fmaxf(o4.z, 0.f); o4.w = fmaxf(o4.w, 0.f);
        }
        *(float4*)(OUT + (size_t)wid * 64 + 4 * cg) = o4;
    }
}

// ---------------------------------------------------------------------------

static inline size_t align256(size_t x) { return (x + 255) & ~(size_t)255; }

extern "C" void kernel_launch(void* const* d_in, const int* in_sizes, int n_in,
                              void* d_out, int out_size, void* d_ws, size_t ws_size,
                              hipStream_t stream) {
    const float* x    = (const float*)d_in[0];
    const int*   esrc = (const int*)d_in[1];
    const int*   edst = (const int*)d_in[2];
    const int E = in_sizes[1];
    const int N = in_sizes[0] / 128;

    const float* W0 = (const float*)d_in[3];
    const float* as0 = (const float*)d_in[4];
    const float* ad0 = (const float*)d_in[5];
    const float* b0 = (const float*)d_in[6];
    const float* W1 = (const float*)d_in[7];
    const float* as1 = (const float*)d_in[8];
    const float* ad1 = (const float*)d_in[9];
    const float* b1 = (const float*)d_in[10];
    const float* W2 = (const float*)d_in[11];
    const float* as2 = (const float*)d_in[12];
    const float* ad2 = (const float*)d_in[13];
    const float* b2 = (const float*)d_in[14];

    const int NB = (N + 127) >> 7;  // buckets of 128 nodes (<=512 for scan)

    // workspace layout
    char* p = (char*)d_ws;
    int* gcnt    = (int*)p; p += align256((size_t)(NB + 1) * 4);
    int* boff    = (int*)p; p += align256((size_t)(NB + 1) * 4);
    int* gfill   = (int*)p; p += align256((size_t)(NB + 1) * 4);
    int* rowptr  = (int*)p; p += align256((size_t)(N + 1) * 4);
    int* csr_src = (int*)p; p += align256((size_t)(E + N) * 4);
    int2* binned = (int2*)p; p += align256((size_t)E * 8);
    __half* h16 = (__half*)p; p += align256((size_t)N * 64 * 2);
    float* sA = (float*)p; p += align256((size_t)N * 4);
    float* dA = (float*)p; p += align256((size_t)N * 4);
    float* XA = (float*)p; p += align256((size_t)N * 64 * 4);
    float* XB = (float*)p; p += align256((size_t)N * 64 * 4);
    float* out = (float*)d_out;

    // ---- CSR build (two-level counting sort) ----
    int nchunk = (E + 4095) / 4096;
    hipMemsetAsync(gcnt, 0, (size_t)(NB + 1) * 4, stream);
    bucket_count_kernel<<<nchunk, 256, NB * 4, stream>>>(edst, gcnt, E, NB);
    bucket_scan_kernel<<<1, 512, 0, stream>>>(gcnt, boff, gfill, rowptr, NB, E, N);
    bucket_place_kernel<<<nchunk, 256, 2 * NB * 4, stream>>>(esrc, edst, gfill, binned, E, NB);
    bucket_build_kernel<<<NB, 256, 0, stream>>>(binned, boff, csr_src, rowptr, N);

    int tile_grid = (N + 63) / 64;
    int agg_grid  = (N + 3) / 4;

    // ---- layer 0: 128 -> 64, relu ----
    gemm_feat_kernel<128><<<tile_grid, 256, 0, stream>>>(x, W0, as0, ad0, h16, sA, dA, N);
    gat_aggregate_kernel<<<agg_grid, 256, 0, stream>>>(h16, sA, dA, rowptr, csr_src, b0, XA, N, 1);

    // ---- layer 1: 64 -> 64, relu ----
    gemm_feat_kernel<64><<<tile_grid, 256, 0, stream>>>(XA, W1, as1, ad1, h16, sA, dA, N);
    gat_aggregate_kernel<<<agg_grid, 256, 0, stream>>>(h16, sA, dA, rowptr, csr_src, b1, XB, N, 1);

    // ---- layer 2: 64 -> 64, no relu ----
    gemm_feat_kernel<64><<<tile_grid, 256, 0, stream>>>(XB, W2, as2, ad2, h16, sA, dA, N);
    gat_aggregate_kernel<<<agg_grid, 256, 0, stream>>>(h16, sA, dA, rowptr, csr_src, b2, out, N, 0);
}